// Round 3
// baseline (236.414 us; speedup 1.0000x reference)
//
#include <hip/hip_runtime.h>

#define BATCH 8192
#define DIM   512
#define NLAB  128

typedef __attribute__((ext_vector_type(4))) float  f32x4;
typedef __attribute__((ext_vector_type(8))) __bf16 bf16x8;

__device__ __forceinline__ unsigned short f2bf(float x) {
  unsigned u = __float_as_uint(x);
  u = (u + 0x7FFFu + ((u >> 16) & 1u)) >> 16;   // RNE
  return (unsigned short)u;
}

__device__ __forceinline__ void load_lds16(const void* g, void* l) {
  __builtin_amdgcn_global_load_lds(
      (__attribute__((address_space(1))) void*)(g),
      (__attribute__((address_space(3))) void*)(l), 16, 0, 0);
}

// monotone float <-> uint encoding (order-preserving for all finite floats)
__device__ __forceinline__ unsigned enc(float f) {
  unsigned u = __float_as_uint(f);
  return u ^ (unsigned)(((int)u >> 31) | 0x80000000);
}
__device__ __forceinline__ float dec(unsigned k) {
  unsigned u = (k & 0x80000000u) ? (k ^ 0x80000000u) : ~k;
  return __uint_as_float(u);
}

// ---------------- prep: fp32 -> bf16, row norms, label histogram ----------------
__global__ __launch_bounds__(256) void prep_kernel(
    const float* __restrict__ X, const int* __restrict__ labels,
    unsigned short* __restrict__ Xb, float* __restrict__ sq,
    int* __restrict__ hist) {
  int wave = threadIdx.x >> 6, lane = threadIdx.x & 63;
  int row = blockIdx.x * 4 + wave;             // 2048 blocks * 4 waves = 8192 rows
  const float4* xr = (const float4*)(X + (size_t)row * DIM);
  float4 a = xr[lane * 2];
  float4 b = xr[lane * 2 + 1];
  float s = a.x*a.x + a.y*a.y + a.z*a.z + a.w*a.w
          + b.x*b.x + b.y*b.y + b.z*b.z + b.w*b.w;
  uint4 p;
  p.x = (unsigned)f2bf(a.x) | ((unsigned)f2bf(a.y) << 16);
  p.y = (unsigned)f2bf(a.z) | ((unsigned)f2bf(a.w) << 16);
  p.z = (unsigned)f2bf(b.x) | ((unsigned)f2bf(b.y) << 16);
  p.w = (unsigned)f2bf(b.z) | ((unsigned)f2bf(b.w) << 16);
  ((uint4*)(Xb + (size_t)row * DIM))[lane] = p;
  #pragma unroll
  for (int off = 32; off > 0; off >>= 1) s += __shfl_down(s, off);
  if (lane == 0) {
    sq[row] = s;
    atomicAdd(&hist[labels[row] & (NLAB - 1)], 1);
  }
}

// ---------------- main: fused X·X^T + masked row max/min (on d^2 surrogate) ----------------
// grid: 512 blocks = 64 i-tiles x 8 j-chunks (chunk = 1024 cols = 8 subtiles of 128)
// -> round-1 schedule (L2-resident: measured FETCH ~34 MB = 4x matrix)
// LDS layout XOR-swizzled: row r's k-chunk c (8 bf16) lives at position c^(r&7)
// -> ds_read_b128 across 16 consecutive rows covers all 32 banks 2-way (free).
__global__ __launch_bounds__(256, 3) void triplet_mfma(
    const unsigned short* __restrict__ Xb, const float* __restrict__ sq,
    const int* __restrict__ labels,
    unsigned* __restrict__ pos_enc, unsigned* __restrict__ neg_enc) {
  __shared__ __align__(16) unsigned short Asm[128 * 64];  // 16 KB
  __shared__ __align__(16) unsigned short Bsm[128 * 64];  // 16 KB
  __shared__ float sqj_s[1024];
  __shared__ int   labj_s[1024];
  __shared__ int   labi_s[128];

  int tid = threadIdx.x;
  int bid = blockIdx.x;
  int It = bid & 63, jc = bid >> 6;
  int i0 = It * 128, jbase = jc * 1024;

  for (int t = tid; t < 1024; t += 256) {
    sqj_s[t]  = sq[jbase + t];
    labj_s[t] = labels[jbase + t];
  }
  if (tid < 128) labi_s[tid] = labels[i0 + tid];
  __syncthreads();

  int wave = tid >> 6, lane = tid & 63;
  int wm = wave >> 1, wn = wave & 1;       // 2x2 wave grid, 64x64 per wave
  int quad = lane >> 4, lc = lane & 15;

  int labi_r[16];
  #pragma unroll
  for (int mi = 0; mi < 4; mi++)
    #pragma unroll
    for (int r = 0; r < 4; r++)
      labi_r[mi * 4 + r] = labi_s[wm * 64 + mi * 16 + quad * 4 + r];

  // running max/min of v = sq_j - 2*dot (sq_i added at the end; monotone in d^2)
  float rpos[16], rneg[16];
  #pragma unroll
  for (int t = 0; t < 16; t++) { rpos[t] = -3e38f; rneg[t] = 3e38f; }

  // staging index precompute (swizzled global k-chunk per lane)
  int rc = lane >> 3;                       // row within 8-row chunk
  int gchunk = (lane & 7) ^ rc;             // XOR swizzle
  int gcol = gchunk * 8;

  for (int js = 0; js < 8; js++) {
    int j0loc = js * 128;
    f32x4 acc[4][4];
    #pragma unroll
    for (int mi = 0; mi < 4; mi++)
      #pragma unroll
      for (int ni = 0; ni < 4; ni++)
        acc[mi][ni] = (f32x4){0.f, 0.f, 0.f, 0.f};

    for (int k0 = 0; k0 < DIM; k0 += 64) {
      // stage A[128][64] and B[128][64] bf16 slices; 16B/lane, wave-uniform LDS base
      #pragma unroll
      for (int t = 0; t < 4; t++) {
        int c = wave * 4 + t;                 // 16 chunks of 8 rows
        int row = c * 8 + rc;
        load_lds16(Xb + (size_t)(i0 + row) * DIM + k0 + gcol, &Asm[c * 512]);
        load_lds16(Xb + (size_t)(jbase + j0loc + row) * DIM + k0 + gcol, &Bsm[c * 512]);
      }
      __syncthreads();
      #pragma unroll
      for (int kk = 0; kk < 64; kk += 32) {
        int kc = kk >> 3;                     // base k-chunk index {0,4}
        int asel = ((kc + quad) ^ (lc & 7)) * 8;
        bf16x8 af[4], bfr[4];
        #pragma unroll
        for (int mi = 0; mi < 4; mi++)
          af[mi] = *(const bf16x8*)&Asm[(wm * 64 + mi * 16 + lc) * 64 + asel];
        #pragma unroll
        for (int ni = 0; ni < 4; ni++)
          bfr[ni] = *(const bf16x8*)&Bsm[(wn * 64 + ni * 16 + lc) * 64 + asel];
        #pragma unroll
        for (int mi = 0; mi < 4; mi++)
          #pragma unroll
          for (int ni = 0; ni < 4; ni++)
            acc[mi][ni] = __builtin_amdgcn_mfma_f32_16x16x32_bf16(
                af[mi], bfr[ni], acc[mi][ni], 0, 0, 0);
      }
      __syncthreads();
    }

    // epilogue: masked running max/min on v = sq_j - 2*dot
    // (diagonal skip intentional: diag d^2 ~ 0 never beats a real positive
    //  d^2 ~ 1024; rows w/o real positives are invalidated by hist)
    float sqj_r[4]; int labj_r[4];
    #pragma unroll
    for (int ni = 0; ni < 4; ni++) {
      int jj = j0loc + wn * 64 + ni * 16 + lc;
      sqj_r[ni]  = sqj_s[jj];
      labj_r[ni] = labj_s[jj];
    }
    #pragma unroll
    for (int mi = 0; mi < 4; mi++) {
      #pragma unroll
      for (int r = 0; r < 4; r++) {
        int li = labi_r[mi * 4 + r];
        float rp = rpos[mi * 4 + r], rn = rneg[mi * 4 + r];
        #pragma unroll
        for (int ni = 0; ni < 4; ni++) {
          float v = fmaf(-2.f, acc[mi][ni][r], sqj_r[ni]);
          bool same_l = (li == labj_r[ni]);
          rp = fmaxf(rp, same_l ? v : -3e38f);
          rn = fminf(rn, same_l ? 3e38f : v);
        }
        rpos[mi * 4 + r] = rp; rneg[mi * 4 + r] = rn;
      }
    }
  }

  // reduce across the 16 lanes of each quad (cols), xor masks 1,2,4,8
  #pragma unroll
  for (int m = 1; m <= 8; m <<= 1) {
    #pragma unroll
    for (int t = 0; t < 16; t++) {
      rpos[t] = fmaxf(rpos[t], __shfl_xor(rpos[t], m));
      rneg[t] = fminf(rneg[t], __shfl_xor(rneg[t], m));
    }
  }

  if (lc == 0) {
    #pragma unroll
    for (int mi = 0; mi < 4; mi++)
      #pragma unroll
      for (int r = 0; r < 4; r++) {
        int row = i0 + wm * 64 + mi * 16 + quad * 4 + r;
        atomicMax(&pos_enc[row], enc(rpos[mi * 4 + r]));
        atomicMin(&neg_enc[row], enc(rneg[mi * 4 + r]));
      }
  }
}

// ---------------- final1: per-row terms -> atomic partial sums ----------------
__global__ __launch_bounds__(256) void final1_kernel(
    const unsigned* __restrict__ pos_enc, const unsigned* __restrict__ neg_enc,
    const float* __restrict__ sq, const int* __restrict__ labels,
    const int* __restrict__ hist, float* __restrict__ sums) {
  int i = blockIdx.x * 256 + threadIdx.x;   // 32 blocks x 256 = 8192
  float p = dec(pos_enc[i]), n = dec(neg_enc[i]);
  float si = sq[i];
  float dp = sqrtf(fmaxf(si + p, 0.f) + 1e-16f);
  float dn = sqrtf(fmaxf(si + n, 0.f) + 1e-16f);
  int c = hist[labels[i] & (NLAB - 1)];
  float term = 0.f, cnt = 0.f;
  if (c >= 2 && c < BATCH) {
    term = fmaxf(dp - dn + 0.3f, 0.f);
    cnt = 1.f;
  }
  #pragma unroll
  for (int off = 32; off > 0; off >>= 1) {
    term += __shfl_down(term, off);
    cnt  += __shfl_down(cnt, off);
  }
  __shared__ float ss[4], sc[4];
  int wave = threadIdx.x >> 6, lane = threadIdx.x & 63;
  if (lane == 0) { ss[wave] = term; sc[wave] = cnt; }
  __syncthreads();
  if (threadIdx.x == 0) {
    atomicAdd(&sums[0], ss[0] + ss[1] + ss[2] + ss[3]);
    atomicAdd(&sums[1], sc[0] + sc[1] + sc[2] + sc[3]);
  }
}

__global__ void final2_kernel(const float* __restrict__ sums, float* __restrict__ out) {
  out[0] = sums[0] / fmaxf(sums[1], 1.f);
}

extern "C" void kernel_launch(void* const* d_in, const int* in_sizes, int n_in,
                              void* d_out, int out_size, void* d_ws, size_t ws_size,
                              hipStream_t stream) {
  const float* X      = (const float*)d_in[0];
  const int*   labels = (const int*)d_in[1];
  float* out = (float*)d_out;
  char* ws = (char*)d_ws;

  unsigned short* Xb  = (unsigned short*)ws;                       // 8 MB
  float*    sq        = (float*)   (ws + (8u << 20));               // 32 KB
  int*      hist      = (int*)     (ws + (8u << 20) + (32u << 10)); // 512 B
  unsigned* pos_enc   = (unsigned*)(ws + (8u << 20) + (64u << 10)); // 32 KB
  unsigned* neg_enc   = (unsigned*)(ws + (8u << 20) + (96u << 10)); // 32 KB
  float*    sums      = (float*)   (ws + (8u << 20) + (128u << 10)); // 8 B

  hipMemsetAsync(hist, 0, NLAB * sizeof(int), stream);
  hipMemsetAsync(pos_enc, 0x00, BATCH * sizeof(unsigned), stream);  // decodes to "always loses" for max
  hipMemsetAsync(neg_enc, 0xFF, BATCH * sizeof(unsigned), stream);  // always loses for min
  hipMemsetAsync(sums, 0, 2 * sizeof(float), stream);
  prep_kernel<<<BATCH / 4, 256, 0, stream>>>(X, labels, Xb, sq, hist);
  triplet_mfma<<<512, 256, 0, stream>>>(Xb, sq, labels, pos_enc, neg_enc);
  final1_kernel<<<BATCH / 256, 256, 0, stream>>>(pos_enc, neg_enc, sq, labels, hist, sums);
  final2_kernel<<<1, 1, 0, stream>>>(sums, out);
}

// Round 4
// 166.062 us; speedup vs baseline: 1.4237x; 1.4237x over previous
//
#include <hip/hip_runtime.h>

#define BATCH 8192
#define DIM   512
#define NLAB  128

typedef __attribute__((ext_vector_type(4))) float  f32x4;
typedef __attribute__((ext_vector_type(8))) __bf16 bf16x8;

__device__ __forceinline__ unsigned short f2bf(float x) {
  unsigned u = __float_as_uint(x);
  u = (u + 0x7FFFu + ((u >> 16) & 1u)) >> 16;   // RNE
  return (unsigned short)u;
}

__device__ __forceinline__ void load_lds16(const void* g, void* l) {
  __builtin_amdgcn_global_load_lds(
      (__attribute__((address_space(1))) void*)(g),
      (__attribute__((address_space(3))) void*)(l), 16, 0, 0);
}

// ---------------- prep: fp32 -> bf16, row norms, label histogram ----------------
__global__ __launch_bounds__(256) void prep_kernel(
    const float* __restrict__ X, const int* __restrict__ labels,
    unsigned short* __restrict__ Xb, float* __restrict__ sq,
    int* __restrict__ hist) {
  int wave = threadIdx.x >> 6, lane = threadIdx.x & 63;
  int row = blockIdx.x * 4 + wave;             // 2048 blocks * 4 waves = 8192 rows
  const float4* xr = (const float4*)(X + (size_t)row * DIM);
  float4 a = xr[lane * 2];
  float4 b = xr[lane * 2 + 1];
  float s = a.x*a.x + a.y*a.y + a.z*a.z + a.w*a.w
          + b.x*b.x + b.y*b.y + b.z*b.z + b.w*b.w;
  uint4 p;
  p.x = (unsigned)f2bf(a.x) | ((unsigned)f2bf(a.y) << 16);
  p.y = (unsigned)f2bf(a.z) | ((unsigned)f2bf(a.w) << 16);
  p.z = (unsigned)f2bf(b.x) | ((unsigned)f2bf(b.y) << 16);
  p.w = (unsigned)f2bf(b.z) | ((unsigned)f2bf(b.w) << 16);
  ((uint4*)(Xb + (size_t)row * DIM))[lane] = p;
  #pragma unroll
  for (int off = 32; off > 0; off >>= 1) s += __shfl_down(s, off);
  if (lane == 0) {
    sq[row] = s;
    atomicAdd(&hist[labels[row] & (NLAB - 1)], 1);
  }
}

// ---------------- main: fused X·X^T + masked row max/min (on d^2 surrogate) ----------------
// grid: 512 blocks = 64 i-tiles x 8 j-chunks (chunk = 1024 cols = 8 subtiles of 128)
// -> round-1 schedule (L2-resident: measured FETCH ~34 MB = 4x matrix)
// LDS layout XOR-swizzled: row r's k-chunk c (8 bf16) lives at position c^(r&7)
// -> ds_read_b128 across 16 consecutive rows covers all 32 banks 2-way (free).
// Epilogue: PLAIN stores into 16 disjoint partial slots (R1-verified, WRITE=1MB).
// Device-scope atomicMax/Min per row was measured at ~150 B HBM RMW each — never again.
__global__ __launch_bounds__(256, 2) void triplet_mfma(
    const unsigned short* __restrict__ Xb, const float* __restrict__ sq,
    const int* __restrict__ labels,
    float* __restrict__ pos_part, float* __restrict__ neg_part) {
  __shared__ __align__(16) unsigned short Asm[128 * 64];  // 16 KB
  __shared__ __align__(16) unsigned short Bsm[128 * 64];  // 16 KB
  __shared__ float sqj_s[1024];
  __shared__ int   labj_s[1024];
  __shared__ int   labi_s[128];

  int tid = threadIdx.x;
  int bid = blockIdx.x;
  int It = bid & 63, jc = bid >> 6;
  int i0 = It * 128, jbase = jc * 1024;

  for (int t = tid; t < 1024; t += 256) {
    sqj_s[t]  = sq[jbase + t];
    labj_s[t] = labels[jbase + t];
  }
  if (tid < 128) labi_s[tid] = labels[i0 + tid];
  __syncthreads();

  int wave = tid >> 6, lane = tid & 63;
  int wm = wave >> 1, wn = wave & 1;       // 2x2 wave grid, 64x64 per wave
  int quad = lane >> 4, lc = lane & 15;

  int labi_r[16];
  #pragma unroll
  for (int mi = 0; mi < 4; mi++)
    #pragma unroll
    for (int r = 0; r < 4; r++)
      labi_r[mi * 4 + r] = labi_s[wm * 64 + mi * 16 + quad * 4 + r];

  // running max/min of v = sq_j - 2*dot (sq_i added at the end; monotone in d^2)
  float rpos[16], rneg[16];
  #pragma unroll
  for (int t = 0; t < 16; t++) { rpos[t] = -3e38f; rneg[t] = 3e38f; }

  // staging index precompute (swizzled global k-chunk per lane)
  int rc = lane >> 3;                       // row within 8-row chunk
  int gchunk = (lane & 7) ^ rc;             // XOR swizzle
  int gcol = gchunk * 8;

  for (int js = 0; js < 8; js++) {
    int j0loc = js * 128;
    f32x4 acc[4][4];
    #pragma unroll
    for (int mi = 0; mi < 4; mi++)
      #pragma unroll
      for (int ni = 0; ni < 4; ni++)
        acc[mi][ni] = (f32x4){0.f, 0.f, 0.f, 0.f};

    for (int k0 = 0; k0 < DIM; k0 += 64) {
      // stage A[128][64] and B[128][64] bf16 slices; 16B/lane, wave-uniform LDS base
      #pragma unroll
      for (int t = 0; t < 4; t++) {
        int c = wave * 4 + t;                 // 16 chunks of 8 rows
        int row = c * 8 + rc;
        load_lds16(Xb + (size_t)(i0 + row) * DIM + k0 + gcol, &Asm[c * 512]);
        load_lds16(Xb + (size_t)(jbase + j0loc + row) * DIM + k0 + gcol, &Bsm[c * 512]);
      }
      __syncthreads();
      #pragma unroll
      for (int kk = 0; kk < 64; kk += 32) {
        int kc = kk >> 3;                     // base k-chunk index {0,4}
        int asel = ((kc + quad) ^ (lc & 7)) * 8;
        bf16x8 af[4], bfr[4];
        #pragma unroll
        for (int mi = 0; mi < 4; mi++)
          af[mi] = *(const bf16x8*)&Asm[(wm * 64 + mi * 16 + lc) * 64 + asel];
        #pragma unroll
        for (int ni = 0; ni < 4; ni++)
          bfr[ni] = *(const bf16x8*)&Bsm[(wn * 64 + ni * 16 + lc) * 64 + asel];
        #pragma unroll
        for (int mi = 0; mi < 4; mi++)
          #pragma unroll
          for (int ni = 0; ni < 4; ni++)
            acc[mi][ni] = __builtin_amdgcn_mfma_f32_16x16x32_bf16(
                af[mi], bfr[ni], acc[mi][ni], 0, 0, 0);
      }
      __syncthreads();
    }

    // epilogue: masked running max/min on v = sq_j - 2*dot
    // (diagonal skip intentional: diag d^2 ~ 0 never beats a real positive
    //  d^2 ~ 1024; rows w/o real positives are invalidated by hist)
    float sqj_r[4]; int labj_r[4];
    #pragma unroll
    for (int ni = 0; ni < 4; ni++) {
      int jj = j0loc + wn * 64 + ni * 16 + lc;
      sqj_r[ni]  = sqj_s[jj];
      labj_r[ni] = labj_s[jj];
    }
    #pragma unroll
    for (int mi = 0; mi < 4; mi++) {
      #pragma unroll
      for (int r = 0; r < 4; r++) {
        int li = labi_r[mi * 4 + r];
        float rp = rpos[mi * 4 + r], rn = rneg[mi * 4 + r];
        #pragma unroll
        for (int ni = 0; ni < 4; ni++) {
          float v = fmaf(-2.f, acc[mi][ni][r], sqj_r[ni]);
          bool same_l = (li == labj_r[ni]);
          rp = fmaxf(rp, same_l ? v : -3e38f);
          rn = fminf(rn, same_l ? 3e38f : v);
        }
        rpos[mi * 4 + r] = rp; rneg[mi * 4 + r] = rn;
      }
    }
  }

  // reduce across the 16 lanes of each quad (cols), xor masks 1,2,4,8
  #pragma unroll
  for (int m = 1; m <= 8; m <<= 1) {
    #pragma unroll
    for (int t = 0; t < 16; t++) {
      rpos[t] = fmaxf(rpos[t], __shfl_xor(rpos[t], m));
      rneg[t] = fminf(rneg[t], __shfl_xor(rneg[t], m));
    }
  }

  if (lc == 0) {
    int slot = jc * 2 + wn;                   // 16 disjoint partial slots
    #pragma unroll
    for (int mi = 0; mi < 4; mi++)
      #pragma unroll
      for (int r = 0; r < 4; r++) {
        int row = i0 + wm * 64 + mi * 16 + quad * 4 + r;
        pos_part[slot * BATCH + row] = rpos[mi * 4 + r];
        neg_part[slot * BATCH + row] = rneg[mi * 4 + r];
      }
  }
}

// ---------------- final: combine slots, per-row terms, global mean (ticketed) ----------------
__global__ __launch_bounds__(256) void final_kernel(
    const float* __restrict__ pos_part, const float* __restrict__ neg_part,
    const float* __restrict__ sq, const int* __restrict__ labels,
    const int* __restrict__ hist, float* __restrict__ sums,
    unsigned* __restrict__ ticket, float* __restrict__ out) {
  int i = blockIdx.x * 256 + threadIdx.x;   // 32 blocks x 256 = 8192
  float p = -3e38f, n = 3e38f;
  #pragma unroll
  for (int s = 0; s < 16; s++) {
    p = fmaxf(p, pos_part[s * BATCH + i]);
    n = fminf(n, neg_part[s * BATCH + i]);
  }
  float si = sq[i];
  float dp = sqrtf(fmaxf(si + p, 0.f) + 1e-16f);
  float dn = sqrtf(fmaxf(si + n, 0.f) + 1e-16f);
  int c = hist[labels[i] & (NLAB - 1)];
  float term = 0.f, cnt = 0.f;
  if (c >= 2 && c < BATCH) {
    term = fmaxf(dp - dn + 0.3f, 0.f);
    cnt = 1.f;
  }
  #pragma unroll
  for (int off = 32; off > 0; off >>= 1) {
    term += __shfl_down(term, off);
    cnt  += __shfl_down(cnt, off);
  }
  __shared__ float ss[4], sc[4];
  int wave = threadIdx.x >> 6, lane = threadIdx.x & 63;
  if (lane == 0) { ss[wave] = term; sc[wave] = cnt; }
  __syncthreads();
  if (threadIdx.x == 0) {
    atomicAdd(&sums[0], ss[0] + ss[1] + ss[2] + ss[3]);
    atomicAdd(&sums[1], sc[0] + sc[1] + sc[2] + sc[3]);
    __threadfence();
    unsigned t = atomicAdd(ticket, 1u);     // all inter-block data flows via atomics
    if (t == 31u) {
      float S = atomicAdd(&sums[0], 0.f);   // atomic read: coherent across XCDs
      float C = atomicAdd(&sums[1], 0.f);
      out[0] = S / fmaxf(C, 1.f);
    }
  }
}

extern "C" void kernel_launch(void* const* d_in, const int* in_sizes, int n_in,
                              void* d_out, int out_size, void* d_ws, size_t ws_size,
                              hipStream_t stream) {
  const float* X      = (const float*)d_in[0];
  const int*   labels = (const int*)d_in[1];
  float* out = (float*)d_out;
  char* ws = (char*)d_ws;

  unsigned short* Xb  = (unsigned short*)ws;                        // 8 MB
  float*    sq        = (float*)   (ws + (8u << 20));                // 32 KB
  // control block: hist[128] | sums[2] | ticket[1]  -> one 528-B memset
  int*      hist      = (int*)     (ws + (8u << 20) + (32u << 10));
  float*    sums      = (float*)   (ws + (8u << 20) + (32u << 10) + 512);
  unsigned* ticket    = (unsigned*)(ws + (8u << 20) + (32u << 10) + 520);
  float*    pos_part  = (float*)   (ws + (8u << 20) + (64u << 10));  // 512 KB
  float*    neg_part  = (float*)   (ws + (8u << 20) + (64u << 10) + (512u << 10)); // 512 KB

  hipMemsetAsync(hist, 0, 528, stream);
  prep_kernel<<<BATCH / 4, 256, 0, stream>>>(X, labels, Xb, sq, hist);
  triplet_mfma<<<512, 256, 0, stream>>>(Xb, sq, labels, pos_part, neg_part);
  final_kernel<<<BATCH / 256, 256, 0, stream>>>(pos_part, neg_part, sq, labels,
                                                hist, sums, ticket, out);
}

// Round 5
// 145.131 us; speedup vs baseline: 1.6290x; 1.1442x over previous
//
#include <hip/hip_runtime.h>

#define BATCH 8192
#define DIM   512

typedef __attribute__((ext_vector_type(4))) float  f32x4;
typedef __attribute__((ext_vector_type(8))) __bf16 bf16x8;

__device__ __forceinline__ unsigned short f2bf(float x) {
  unsigned u = __float_as_uint(x);
  u = (u + 0x7FFFu + ((u >> 16) & 1u)) >> 16;   // RNE
  return (unsigned short)u;
}

__device__ __forceinline__ void load_lds16(const void* g, void* l) {
  __builtin_amdgcn_global_load_lds(
      (__attribute__((address_space(1))) void*)(g),
      (__attribute__((address_space(3))) void*)(l), 16, 0, 0);
}

// ---------------- prep: fp32 -> bf16, row norms; zero the control block ----------------
// hist is GONE: validity now comes from the mined sentinels (diagonal masked in epilogue).
// 8192 device-scope atomicAdds onto 4 cache lines (R4) were the suspected tail cost.
__global__ __launch_bounds__(256) void prep_kernel(
    const float* __restrict__ X, unsigned short* __restrict__ Xb,
    float* __restrict__ sq, float* __restrict__ ctrl) {
  if (blockIdx.x == 0 && threadIdx.x == 0) {
    ctrl[0] = 0.f; ctrl[1] = 0.f;              // sums
    ((unsigned*)ctrl)[2] = 0u;                 // ticket (stream-order flush -> visible to final)
  }
  int wave = threadIdx.x >> 6, lane = threadIdx.x & 63;
  int row = blockIdx.x * 4 + wave;             // 2048 blocks * 4 waves = 8192 rows
  const float4* xr = (const float4*)(X + (size_t)row * DIM);
  float4 a = xr[lane * 2];
  float4 b = xr[lane * 2 + 1];
  float s = a.x*a.x + a.y*a.y + a.z*a.z + a.w*a.w
          + b.x*b.x + b.y*b.y + b.z*b.z + b.w*b.w;
  uint4 p;
  p.x = (unsigned)f2bf(a.x) | ((unsigned)f2bf(a.y) << 16);
  p.y = (unsigned)f2bf(a.z) | ((unsigned)f2bf(a.w) << 16);
  p.z = (unsigned)f2bf(b.x) | ((unsigned)f2bf(b.y) << 16);
  p.w = (unsigned)f2bf(b.z) | ((unsigned)f2bf(b.w) << 16);
  ((uint4*)(Xb + (size_t)row * DIM))[lane] = p;
  #pragma unroll
  for (int off = 32; off > 0; off >>= 1) s += __shfl_down(s, off);
  if (lane == 0) sq[row] = s;
}

// Per-js epilogue, templated on whether this wave-tile straddles the true diagonal
// (only 1 of 8 wave-tiles in 64/512 blocks — keeps the j!=i compare off the hot path).
template<bool DIAG>
__device__ __forceinline__ void tile_epilogue(
    const f32x4 (&acc)[4][8],
    const float* __restrict__ sqj_s, const int* __restrict__ labj_s,
    const int* __restrict__ labi_s,
    int j0loc, int wn, int wm, int lc, int quad, int i0, int jbase,
    float (&rpos)[16], float (&rneg)[16]) {
  float sqj_r[8]; int labj_r[8]; int jg_r[8];
  #pragma unroll
  for (int ni = 0; ni < 8; ni++) {
    int jj = j0loc + wn * 128 + ni * 16 + lc;
    sqj_r[ni]  = sqj_s[jj];
    labj_r[ni] = labj_s[jj];
    jg_r[ni]   = jbase + jj;
  }
  #pragma unroll
  for (int mi = 0; mi < 4; mi++) {
    #pragma unroll
    for (int r = 0; r < 4; r++) {
      int idx = mi * 4 + r;
      int li = labi_s[wm * 64 + mi * 16 + quad * 4 + r];
      int ii = i0 + wm * 64 + mi * 16 + quad * 4 + r;
      float rp = rpos[idx], rn = rneg[idx];
      #pragma unroll
      for (int ni = 0; ni < 8; ni++) {
        float v = fmaf(-2.f, acc[mi][ni][r], sqj_r[ni]);
        bool same = (li == labj_r[ni]);
        bool posok = DIAG ? (same && (jg_r[ni] != ii)) : same;
        rp = fmaxf(rp, posok ? v : -3e38f);
        rn = fminf(rn, same ? 3e38f : v);
      }
      rpos[idx] = rp; rneg[idx] = rn;
    }
  }
}

// ---------------- main: fused X·X^T + masked row max/min (on d^2 surrogate) ----------------
// grid: 512 blocks = 64 i-tiles x 8 j-chunks (R1/R4-proven L2 schedule, FETCH ~33MB)
// Block tile 128x256 per js (4 js = 1024-wide slab). Wave tile 64x128 (acc 4x8):
// frag reads per MFMA 0.375 vs 0.5 — attacks the binding LDS-read pipe.
// XOR-swizzled LDS (verified 0 conflicts). Plain stores to 16 disjoint slots.
__global__ __launch_bounds__(256, 2) void triplet_mfma(
    const unsigned short* __restrict__ Xb, const float* __restrict__ sq,
    const int* __restrict__ labels,
    float* __restrict__ pos_part, float* __restrict__ neg_part) {
  __shared__ __align__(16) unsigned short Asm[128 * 64];  // 16 KB
  __shared__ __align__(16) unsigned short Bsm[256 * 64];  // 32 KB
  __shared__ float sqj_s[1024];
  __shared__ int   labj_s[1024];
  __shared__ int   labi_s[128];

  int tid = threadIdx.x;
  int bid = blockIdx.x;
  int It = bid & 63, jc = bid >> 6;
  int i0 = It * 128, jbase = jc * 1024;

  for (int t = tid; t < 1024; t += 256) {
    sqj_s[t]  = sq[jbase + t];
    labj_s[t] = labels[jbase + t];
  }
  if (tid < 128) labi_s[tid] = labels[i0 + tid];
  __syncthreads();

  int wave = tid >> 6, lane = tid & 63;
  int wm = wave >> 1, wn = wave & 1;       // 2x2 wave grid: rows wm*64, cols wn*128
  int quad = lane >> 4, lc = lane & 15;

  float rpos[16], rneg[16];
  #pragma unroll
  for (int t = 0; t < 16; t++) { rpos[t] = -3e38f; rneg[t] = 3e38f; }

  int rc = lane >> 3;                       // row within 8-row staging chunk
  int gcol = ((lane & 7) ^ rc) * 8;         // XOR swizzle (verified: 0 conflicts)

  for (int js = 0; js < 4; js++) {
    int j0loc = js * 256;
    f32x4 acc[4][8];
    #pragma unroll
    for (int mi = 0; mi < 4; mi++)
      #pragma unroll
      for (int ni = 0; ni < 8; ni++)
        acc[mi][ni] = (f32x4){0.f, 0.f, 0.f, 0.f};

    for (int k0 = 0; k0 < DIM; k0 += 64) {
      // A: 16 chunks of (8 rows x 64), 4 per wave; B: 32 chunks, 8 per wave
      #pragma unroll
      for (int t = 0; t < 4; t++) {
        int c = wave * 4 + t;
        int row = c * 8 + rc;
        load_lds16(Xb + (size_t)(i0 + row) * DIM + k0 + gcol, &Asm[c * 512]);
      }
      #pragma unroll
      for (int t = 0; t < 8; t++) {
        int c = wave * 8 + t;
        int row = c * 8 + rc;
        load_lds16(Xb + (size_t)(jbase + j0loc + row) * DIM + k0 + gcol, &Bsm[c * 512]);
      }
      __syncthreads();
      #pragma unroll
      for (int kk = 0; kk < 64; kk += 32) {
        int kc = kk >> 3;
        int asel = ((kc + quad) ^ (lc & 7)) * 8;
        bf16x8 af[4], bfr[8];
        #pragma unroll
        for (int mi = 0; mi < 4; mi++)
          af[mi] = *(const bf16x8*)&Asm[(wm * 64 + mi * 16 + lc) * 64 + asel];
        #pragma unroll
        for (int ni = 0; ni < 8; ni++)
          bfr[ni] = *(const bf16x8*)&Bsm[(wn * 128 + ni * 16 + lc) * 64 + asel];
        #pragma unroll
        for (int mi = 0; mi < 4; mi++)
          #pragma unroll
          for (int ni = 0; ni < 8; ni++)
            acc[mi][ni] = __builtin_amdgcn_mfma_f32_16x16x32_bf16(
                af[mi], bfr[ni], acc[mi][ni], 0, 0, 0);
      }
      __syncthreads();
    }

    // does this wave's 64x128 tile straddle the true diagonal?
    int ilo = i0 + wm * 64, jlo = jbase + j0loc + wn * 128;
    bool has_diag = (ilo < jlo + 128) && (jlo < ilo + 64);
    if (has_diag)
      tile_epilogue<true >(acc, sqj_s, labj_s, labi_s, j0loc, wn, wm, lc, quad, i0, jbase, rpos, rneg);
    else
      tile_epilogue<false>(acc, sqj_s, labj_s, labi_s, j0loc, wn, wm, lc, quad, i0, jbase, rpos, rneg);
  }

  // reduce across the 16 lanes of each quad (cols), xor masks 1,2,4,8
  #pragma unroll
  for (int m = 1; m <= 8; m <<= 1) {
    #pragma unroll
    for (int t = 0; t < 16; t++) {
      rpos[t] = fmaxf(rpos[t], __shfl_xor(rpos[t], m));
      rneg[t] = fminf(rneg[t], __shfl_xor(rneg[t], m));
    }
  }

  if (lc == 0) {
    int slot = jc * 2 + wn;                   // 16 disjoint partial slots (plain stores)
    #pragma unroll
    for (int mi = 0; mi < 4; mi++)
      #pragma unroll
      for (int r = 0; r < 4; r++) {
        int row = i0 + wm * 64 + mi * 16 + quad * 4 + r;
        pos_part[slot * BATCH + row] = rpos[mi * 4 + r];
        neg_part[slot * BATCH + row] = rneg[mi * 4 + r];
      }
  }
}

// ---------------- final: combine slots, per-row terms, global mean (ticketed) ----------------
// validity from sentinels: rpos==-3e38 <=> no off-diagonal positive; rneg==3e38 <=> no negative.
__global__ __launch_bounds__(256) void final_kernel(
    const float* __restrict__ pos_part, const float* __restrict__ neg_part,
    const float* __restrict__ sq, float* __restrict__ ctrl,
    float* __restrict__ out) {
  int i = blockIdx.x * 256 + threadIdx.x;   // 32 blocks x 256 = 8192
  float p = -3e38f, n = 3e38f;
  #pragma unroll
  for (int s = 0; s < 16; s++) {
    p = fmaxf(p, pos_part[s * BATCH + i]);
    n = fminf(n, neg_part[s * BATCH + i]);
  }
  float term = 0.f, cnt = 0.f;
  if (p > -1e37f && n < 1e37f) {
    float si = sq[i];
    float dp = sqrtf(fmaxf(si + p, 0.f) + 1e-16f);
    float dn = sqrtf(fmaxf(si + n, 0.f) + 1e-16f);
    term = fmaxf(dp - dn + 0.3f, 0.f);
    cnt = 1.f;
  }
  #pragma unroll
  for (int off = 32; off > 0; off >>= 1) {
    term += __shfl_down(term, off);
    cnt  += __shfl_down(cnt, off);
  }
  __shared__ float ss[4], sc[4];
  int wave = threadIdx.x >> 6, lane = threadIdx.x & 63;
  if (lane == 0) { ss[wave] = term; sc[wave] = cnt; }
  __syncthreads();
  if (threadIdx.x == 0) {
    atomicAdd(&ctrl[0], ss[0] + ss[1] + ss[2] + ss[3]);
    atomicAdd(&ctrl[1], sc[0] + sc[1] + sc[2] + sc[3]);
    __threadfence();
    unsigned t = atomicAdd((unsigned*)&ctrl[2], 1u);
    if (t == 31u) {
      float S = atomicAdd(&ctrl[0], 0.f);   // atomic read: coherent across XCDs
      float C = atomicAdd(&ctrl[1], 0.f);
      out[0] = S / fmaxf(C, 1.f);
    }
  }
}

extern "C" void kernel_launch(void* const* d_in, const int* in_sizes, int n_in,
                              void* d_out, int out_size, void* d_ws, size_t ws_size,
                              hipStream_t stream) {
  const float* X      = (const float*)d_in[0];
  const int*   labels = (const int*)d_in[1];
  float* out = (float*)d_out;
  char* ws = (char*)d_ws;

  unsigned short* Xb  = (unsigned short*)ws;                        // 8 MB
  float*    sq        = (float*)(ws + (8u << 20));                   // 32 KB
  float*    ctrl      = (float*)(ws + (8u << 20) + (32u << 10));     // sums[2] + ticket
  float*    pos_part  = (float*)(ws + (8u << 20) + (64u << 10));     // 512 KB
  float*    neg_part  = (float*)(ws + (8u << 20) + (64u << 10) + (512u << 10)); // 512 KB

  prep_kernel<<<BATCH / 4, 256, 0, stream>>>(X, Xb, sq, ctrl);
  triplet_mfma<<<512, 256, 0, stream>>>(Xb, sq, labels, pos_part, neg_part);
  final_kernel<<<BATCH / 256, 256, 0, stream>>>(pos_part, neg_part, sq, ctrl, out);
}